// Round 1
// baseline (740.820 us; speedup 1.0000x reference)
//
#include <hip/hip_runtime.h>
#include <hip/hip_bf16.h>

// Problem constants
#define B 64
#define S 4096
#define H 256
#define KT 32  // K-chunk for scores GEMM

// ---------------------------------------------------------------------------
// Wk transpose: WkT[g][h] = Wk[h][g]  (so scores GEMM loads B-tiles coalesced)
// grid(8,8), block(32,8)
__global__ __launch_bounds__(256) void transpose256(const float* __restrict__ in,
                                                    float* __restrict__ out) {
    __shared__ float tile[32][33];
    int bx = blockIdx.x * 32, by = blockIdx.y * 32;
    int tx = threadIdx.x, ty = threadIdx.y;
    #pragma unroll
    for (int i = 0; i < 32; i += 8)
        tile[ty + i][tx] = in[(by + ty + i) * H + bx + tx];
    __syncthreads();
    #pragma unroll
    for (int i = 0; i < 32; i += 8)
        out[(bx + ty + i) * H + by + tx] = tile[tx][ty + i];
}

// ---------------------------------------------------------------------------
// q_proj[b][h] = sum_g query[b][g] * Wq[h][g]
// grid(64), block(256): thread h computes one output; query row staged in LDS.
__global__ __launch_bounds__(256) void qproj_kernel(const float* __restrict__ query,
                                                    const float* __restrict__ Wq,
                                                    float* __restrict__ qp) {
    int b = blockIdx.x, h = threadIdx.x;
    __shared__ float qrow[H];
    qrow[h] = query[b * H + h];
    __syncthreads();
    const float* wrow = Wq + h * H;
    float acc = 0.f;
    #pragma unroll 8
    for (int g = 0; g < H; g += 4) {
        float4 w = *(const float4*)(wrow + g);
        acc += w.x * qrow[g] + w.y * qrow[g + 1] + w.z * qrow[g + 2] + w.w * qrow[g + 3];
    }
    qp[b * H + h] = acc;
}

// ---------------------------------------------------------------------------
// scores[b][s] = sum_h V[h] * tanh(qp[b][h] + sum_g keys[b][s][g]*Wk[h][g])
// Tiled GEMM (M=64 rows of s per block, N=256 all h, K=256 in chunks of 32)
// with fused tanh + V-dot epilogue. grid(64 s-chunks, 64 b), block(256).
// Thread (tx=tid&31, ty=tid>>5) owns 8 rows x 8 cols; cols = {tx*4+j, 128+tx*4+j}.
__global__ __launch_bounds__(256) void scores_kernel(const float* __restrict__ keys,
                                                     const float* __restrict__ WkT,
                                                     const float* __restrict__ qp,
                                                     const float* __restrict__ V,
                                                     float* __restrict__ scores) {
    int b = blockIdx.y;
    int s0 = blockIdx.x * 64;
    int tid = threadIdx.x;
    int tx = tid & 31, ty = tid >> 5;

    __shared__ float sA[KT][72];   // keys^T tile: [k][row], padded (288B rows, 16B-aligned)
    __shared__ float sB[KT][H];    // WkT tile: [k][col]

    float acc[8][8];
    #pragma unroll
    for (int i = 0; i < 8; ++i)
        #pragma unroll
        for (int j = 0; j < 8; ++j) acc[i][j] = 0.f;

    // epilogue constants for this thread's 8 columns
    float vreg[8], qreg[8];
    #pragma unroll
    for (int j = 0; j < 4; ++j) {
        int c = tx * 4 + j;
        vreg[j] = V[c];
        qreg[j] = qp[b * H + c];
        int c2 = 128 + tx * 4 + j;
        vreg[4 + j] = V[c2];
        qreg[4 + j] = qp[b * H + c2];
    }

    const float* keyBase = keys + ((size_t)(b * S + s0)) * H;

    int qa = tid & 7, ra = tid >> 3;       // A-tile staging: 8 float4 cols x 32 rows
    int kb = tid >> 6, cb = (tid & 63) * 4; // B-tile staging

    for (int k0 = 0; k0 < H; k0 += KT) {
        // stage A (keys 64x32 -> transposed sA[k][r])
        #pragma unroll
        for (int it = 0; it < 2; ++it) {
            int r = ra + it * 32;
            float4 a4 = *(const float4*)(keyBase + (size_t)r * H + k0 + qa * 4);
            sA[qa * 4 + 0][r] = a4.x;
            sA[qa * 4 + 1][r] = a4.y;
            sA[qa * 4 + 2][r] = a4.z;
            sA[qa * 4 + 3][r] = a4.w;
        }
        // stage B (WkT rows, direct coalesced copy)
        #pragma unroll
        for (int it = 0; it < 8; ++it) {
            int k = kb + it * 4;
            *(float4*)&sB[k][cb] = *(const float4*)(WkT + (size_t)(k0 + k) * H + cb);
        }
        __syncthreads();

        #pragma unroll
        for (int k = 0; k < KT; ++k) {
            float a[8], bb[8];
            *(float4*)&a[0] = *(const float4*)&sA[k][ty * 8];
            *(float4*)&a[4] = *(const float4*)&sA[k][ty * 8 + 4];
            *(float4*)&bb[0] = *(const float4*)&sB[k][tx * 4];
            *(float4*)&bb[4] = *(const float4*)&sB[k][128 + tx * 4];
            #pragma unroll
            for (int i = 0; i < 8; ++i)
                #pragma unroll
                for (int j = 0; j < 8; ++j) acc[i][j] += a[i] * bb[j];
        }
        __syncthreads();
    }

    // epilogue: p_i = sum_j V[c]*tanh(qp[c] + acc[i][j]); reduce across tx
    #pragma unroll
    for (int i = 0; i < 8; ++i) {
        float p = 0.f;
        #pragma unroll
        for (int j = 0; j < 8; ++j) {
            float x = qreg[j] + acc[i][j];
            // tanh(x) = 1 - 2/(e^{2x}+1); safe at +-inf
            float t = 1.f - 2.f / (__expf(2.f * x) + 1.f);
            p += vreg[j] * t;
        }
        p += __shfl_xor(p, 16);
        p += __shfl_xor(p, 8);
        p += __shfl_xor(p, 4);
        p += __shfl_xor(p, 2);
        p += __shfl_xor(p, 1);
        if (tx == 0) scores[b * S + s0 + ty * 8 + i] = p;
    }
}

// ---------------------------------------------------------------------------
// softmax over each row of scores [B][S]; writes weights. grid(64), block(256).
__global__ __launch_bounds__(256) void softmax_kernel(const float* __restrict__ scores,
                                                      float* __restrict__ weights) {
    __shared__ float sd[S];
    __shared__ float redm[4], reds[4];
    int b = blockIdx.x, tid = threadIdx.x;
    const float* src = scores + b * S;

    float m = -1e30f;
    for (int i = tid * 4; i < S; i += 1024) {
        float4 v = *(const float4*)(src + i);
        *(float4*)(sd + i) = v;
        m = fmaxf(m, fmaxf(fmaxf(v.x, v.y), fmaxf(v.z, v.w)));
    }
    #pragma unroll
    for (int off = 32; off; off >>= 1) m = fmaxf(m, __shfl_xor(m, off));
    if ((tid & 63) == 0) redm[tid >> 6] = m;
    __syncthreads();
    float M = fmaxf(fmaxf(redm[0], redm[1]), fmaxf(redm[2], redm[3]));

    float sum = 0.f;
    for (int i = tid * 4; i < S; i += 1024) {
        float4 v = *(float4*)(sd + i);
        v.x = __expf(v.x - M);
        v.y = __expf(v.y - M);
        v.z = __expf(v.z - M);
        v.w = __expf(v.w - M);
        sum += v.x + v.y + v.z + v.w;
        *(float4*)(sd + i) = v;
    }
    #pragma unroll
    for (int off = 32; off; off >>= 1) sum += __shfl_xor(sum, off);
    if ((tid & 63) == 0) reds[tid >> 6] = sum;
    __syncthreads();
    float inv = 1.f / (reds[0] + reds[1] + reds[2] + reds[3]);

    float* dst = weights + b * S;
    for (int i = tid * 4; i < S; i += 1024) {
        float4 v = *(float4*)(sd + i);
        v.x *= inv; v.y *= inv; v.z *= inv; v.w *= inv;
        *(float4*)(dst + i) = v;
    }
}

// ---------------------------------------------------------------------------
// context[b][h] = sum_s weights[b][s] * keys[b][s][h]
// grid(16 s-chunks, 64 b), block(256). Each thread owns 4 h for 1 of 4 s-lanes,
// LDS-reduce across s-lanes, then atomicAdd into zero-initialized ctx.
__global__ __launch_bounds__(256) void context_kernel(const float* __restrict__ keys,
                                                      const float* __restrict__ weights,
                                                      float* __restrict__ ctx) {
    int b = blockIdx.y;
    int chunk = blockIdx.x;  // 16 chunks x 256 s
    int tid = threadIdx.x;

    __shared__ float w[256];
    w[tid] = weights[b * S + chunk * 256 + tid];
    __syncthreads();

    int sl = tid >> 6;        // 0..3 s-lane
    int h4 = (tid & 63) * 4;  // 0..252

    float4 acc = {0.f, 0.f, 0.f, 0.f};
    const float* kb = keys + ((size_t)(b * S + chunk * 256)) * H;
    for (int s = sl; s < 256; s += 4) {
        float ws = w[s];
        float4 k4 = *(const float4*)(kb + (size_t)s * H + h4);
        acc.x += ws * k4.x;
        acc.y += ws * k4.y;
        acc.z += ws * k4.z;
        acc.w += ws * k4.w;
    }

    __shared__ float4 part[4][64];
    part[sl][tid & 63] = acc;
    __syncthreads();
    if (sl == 0) {
        float4 t = part[0][tid];
        #pragma unroll
        for (int g = 1; g < 4; ++g) {
            float4 p = part[g][tid];
            t.x += p.x; t.y += p.y; t.z += p.z; t.w += p.w;
        }
        atomicAdd(&ctx[b * H + h4 + 0], t.x);
        atomicAdd(&ctx[b * H + h4 + 1], t.y);
        atomicAdd(&ctx[b * H + h4 + 2], t.z);
        atomicAdd(&ctx[b * H + h4 + 3], t.w);
    }
}

// ---------------------------------------------------------------------------
extern "C" void kernel_launch(void* const* d_in, const int* in_sizes, int n_in,
                              void* d_out, int out_size, void* d_ws, size_t ws_size,
                              hipStream_t stream) {
    const float* query = (const float*)d_in[0];  // [B,H]
    const float* keys  = (const float*)d_in[1];  // [B,S,H]
    const float* Wq    = (const float*)d_in[2];  // [H,H]
    const float* Wk    = (const float*)d_in[3];  // [H,H]
    const float* V     = (const float*)d_in[4];  // [H]

    float* ctx     = (float*)d_out;            // [B,H]   = 16384 floats
    float* weights = (float*)d_out + B * H;    // [B,S]   = 262144 floats

    float* qp     = (float*)d_ws;              // 16384 floats
    float* WkT    = qp + B * H;                // 65536 floats
    float* scores = WkT + H * H;               // 262144 floats

    hipMemsetAsync(ctx, 0, B * H * sizeof(float), stream);
    transpose256<<<dim3(8, 8), dim3(32, 8), 0, stream>>>(Wk, WkT);
    qproj_kernel<<<B, 256, 0, stream>>>(query, Wq, qp);
    scores_kernel<<<dim3(S / 64, B), 256, 0, stream>>>(keys, WkT, qp, V, scores);
    softmax_kernel<<<B, 256, 0, stream>>>(scores, weights);
    context_kernel<<<dim3(16, B), 256, 0, stream>>>(keys, weights, ctx);
}

// Round 4
// 531.404 us; speedup vs baseline: 1.3941x; 1.3941x over previous
//
#include <hip/hip_runtime.h>
#include <hip/hip_bf16.h>

#define B 64
#define S 4096
#define H 256
#define BM 128
#define BK 32

typedef short bf16x8 __attribute__((ext_vector_type(8)));
typedef float f32x4 __attribute__((ext_vector_type(4)));

// ---------------------------------------------------------------------------
// Split Wk (f32 [H][H], K-major rows) into hi/lo bf16 planes.
// hi = truncate-to-bf16(x), lo = truncate-to-bf16(x - hi). hi+lo carries ~16
// mantissa bits; 3-pass MFMA (hh+hl+lh) then gives ~fp32 GEMM accuracy.
__global__ __launch_bounds__(256) void wk_split(const float* __restrict__ Wk,
                                                unsigned short* __restrict__ WkHi,
                                                unsigned short* __restrict__ WkLo) {
    int i = (blockIdx.x * 256 + threadIdx.x) * 4;
    float4 x = *(const float4*)(Wk + i);
    float f[4] = {x.x, x.y, x.z, x.w};
    unsigned int hw[2], lw[2];
    #pragma unroll
    for (int j = 0; j < 2; ++j) {
        unsigned int u0 = __float_as_uint(f[2 * j]);
        unsigned int u1 = __float_as_uint(f[2 * j + 1]);
        float h0 = __uint_as_float(u0 & 0xFFFF0000u);
        float h1 = __uint_as_float(u1 & 0xFFFF0000u);
        unsigned int l0 = __float_as_uint(f[2 * j] - h0) >> 16;
        unsigned int l1 = __float_as_uint(f[2 * j + 1] - h1) >> 16;
        hw[j] = (u0 >> 16) | (u1 & 0xFFFF0000u);
        lw[j] = l0 | (l1 << 16);
    }
    *(uint2*)(WkHi + i) = make_uint2(hw[0], hw[1]);
    *(uint2*)(WkLo + i) = make_uint2(lw[0], lw[1]);
}

// ---------------------------------------------------------------------------
// q_proj[b][h] = sum_g query[b][g] * Wq[h][g]
__global__ __launch_bounds__(256) void qproj_kernel(const float* __restrict__ query,
                                                    const float* __restrict__ Wq,
                                                    float* __restrict__ qp) {
    int b = blockIdx.x, h = threadIdx.x;
    __shared__ float qrow[H];
    qrow[h] = query[b * H + h];
    __syncthreads();
    const float* wrow = Wq + h * H;
    float acc = 0.f;
    #pragma unroll 8
    for (int g = 0; g < H; g += 4) {
        float4 w = *(const float4*)(wrow + g);
        acc += w.x * qrow[g] + w.y * qrow[g + 1] + w.z * qrow[g + 2] + w.w * qrow[g + 3];
    }
    qp[b * H + h] = acc;
}

// ---------------------------------------------------------------------------
// scores[b][s] = sum_h V[h] * tanh(qp[b][h] + sum_g keys[b][s][g]*Wk[h][g])
// Split-bf16 MFMA GEMM: block = 128 s-rows x 256 h-cols, K=256 in chunks of 32.
// 512 threads = 8 waves as 2(M) x 4(N); wave tile 64x64 = 4x4 16x16 fragments.
// LDS rows padded to 40 bf16 (80 B) -> 2-way bank aliasing on ds_read_b128 (free).
__global__ __launch_bounds__(512) void scores_kernel(
    const float* __restrict__ keys,
    const unsigned short* __restrict__ WkHi,
    const unsigned short* __restrict__ WkLo,
    const float* __restrict__ qp,
    const float* __restrict__ V,
    float* __restrict__ scores)
{
    __shared__ unsigned short Ahi[BM][40], Alo[BM][40];
    __shared__ unsigned short Bhi[H][40], Blo[H][40];
    __shared__ float part[4][BM];

    const int b  = blockIdx.y;
    const int s0 = blockIdx.x * BM;
    const int tid  = threadIdx.x;
    const int lane = tid & 63;
    const int wid  = tid >> 6;
    const int lr = lane & 15, lg = lane >> 4;
    const int mg = wid >> 2, ng = wid & 3;  // wave tile origin: (mg*64, ng*64)

    // staging thread mapping
    const int ar = tid >> 2;             // A row 0..127 (4 threads/row)
    const int ak = (tid & 3) * 8;        // A k-offset {0,8,16,24}
    const int br = tid >> 1;             // B row 0..255 (2 threads/row)
    const int bk = (tid & 1) * 16;       // B k-offset {0,16}

    const float* aptr = keys + ((size_t)(b * S + s0 + ar)) * H + ak;
    const unsigned short* bhptr = WkHi + br * H + bk;
    const unsigned short* blptr = WkLo + br * H + bk;

    f32x4 acc[4][4];
    #pragma unroll
    for (int mi = 0; mi < 4; ++mi)
        #pragma unroll
        for (int ni = 0; ni < 4; ++ni) acc[mi][ni] = (f32x4){0.f, 0.f, 0.f, 0.f};

    float qv[4], vv[4];
    #pragma unroll
    for (int ni = 0; ni < 4; ++ni) {
        int c = ng * 64 + ni * 16 + lr;
        qv[ni] = qp[b * H + c];
        vv[ni] = V[c];
    }

    // prologue: load chunk 0 into regs
    float4 a0 = *(const float4*)(aptr);
    float4 a1 = *(const float4*)(aptr + 4);
    uint4 bh0 = *(const uint4*)(bhptr);
    uint4 bh1 = *(const uint4*)(bhptr + 8);
    uint4 bl0 = *(const uint4*)(blptr);
    uint4 bl1 = *(const uint4*)(blptr + 8);

    for (int t = 0; t < 8; ++t) {
        // --- stage chunk t regs -> LDS (f32 -> hi/lo bf16 for A) ---
        float f[8] = {a0.x, a0.y, a0.z, a0.w, a1.x, a1.y, a1.z, a1.w};
        unsigned int hw[4], lw[4];
        #pragma unroll
        for (int j = 0; j < 4; ++j) {
            unsigned int u0 = __float_as_uint(f[2 * j]);
            unsigned int u1 = __float_as_uint(f[2 * j + 1]);
            float h0 = __uint_as_float(u0 & 0xFFFF0000u);
            float h1 = __uint_as_float(u1 & 0xFFFF0000u);
            unsigned int l0 = __float_as_uint(f[2 * j] - h0) >> 16;
            unsigned int l1 = __float_as_uint(f[2 * j + 1] - h1) >> 16;
            hw[j] = (u0 >> 16) | (u1 & 0xFFFF0000u);
            lw[j] = l0 | (l1 << 16);
        }
        *(uint4*)&Ahi[ar][ak] = make_uint4(hw[0], hw[1], hw[2], hw[3]);
        *(uint4*)&Alo[ar][ak] = make_uint4(lw[0], lw[1], lw[2], lw[3]);
        *(uint4*)&Bhi[br][bk] = bh0;
        *(uint4*)&Bhi[br][bk + 8] = bh1;
        *(uint4*)&Blo[br][bk] = bl0;
        *(uint4*)&Blo[br][bk + 8] = bl1;

        // issue prefetch for chunk t+1 (completes under compute of chunk t)
        if (t < 7) {
            int k1 = (t + 1) * BK;
            a0 = *(const float4*)(aptr + k1);
            a1 = *(const float4*)(aptr + k1 + 4);
            bh0 = *(const uint4*)(bhptr + k1);
            bh1 = *(const uint4*)(bhptr + k1 + 8);
            bl0 = *(const uint4*)(blptr + k1);
            bl1 = *(const uint4*)(blptr + k1 + 8);
        }
        __syncthreads();

        // --- compute chunk t ---
        bf16x8 bhf[4], blf[4];
        #pragma unroll
        for (int ni = 0; ni < 4; ++ni) {
            bhf[ni] = *(const bf16x8*)&Bhi[ng * 64 + ni * 16 + lr][lg * 8];
            blf[ni] = *(const bf16x8*)&Blo[ng * 64 + ni * 16 + lr][lg * 8];
        }
        #pragma unroll
        for (int mi = 0; mi < 4; ++mi) {
            bf16x8 ah = *(const bf16x8*)&Ahi[mg * 64 + mi * 16 + lr][lg * 8];
            bf16x8 al = *(const bf16x8*)&Alo[mg * 64 + mi * 16 + lr][lg * 8];
            #pragma unroll
            for (int ni = 0; ni < 4; ++ni) {
                acc[mi][ni] = __builtin_amdgcn_mfma_f32_16x16x32_bf16(ah, bhf[ni], acc[mi][ni], 0, 0, 0);
                acc[mi][ni] = __builtin_amdgcn_mfma_f32_16x16x32_bf16(ah, blf[ni], acc[mi][ni], 0, 0, 0);
                acc[mi][ni] = __builtin_amdgcn_mfma_f32_16x16x32_bf16(al, bhf[ni], acc[mi][ni], 0, 0, 0);
            }
        }
        __syncthreads();
    }

    // --- epilogue: p[s] = sum_h V[h]*tanh(qp[h] + C[s,h]) ---
    // C/D layout: col = lane&15, row = (lane>>4)*4 + reg  [m89-verified]
    #pragma unroll
    for (int mi = 0; mi < 4; ++mi) {
        #pragma unroll
        for (int r = 0; r < 4; ++r) {
            float p = 0.f;
            #pragma unroll
            for (int ni = 0; ni < 4; ++ni) {
                float x = qv[ni] + acc[mi][ni][r];
                float e = __expf(2.f * x);
                float tnh = 1.f - 2.f / (e + 1.f);
                p += vv[ni] * tnh;
            }
            p += __shfl_xor(p, 1);
            p += __shfl_xor(p, 2);
            p += __shfl_xor(p, 4);
            p += __shfl_xor(p, 8);
            if (lr == 0) part[ng][mg * 64 + mi * 16 + lg * 4 + r] = p;
        }
    }
    __syncthreads();
    if (tid < BM) {
        float sc = part[0][tid] + part[1][tid] + part[2][tid] + part[3][tid];
        scores[(size_t)b * S + s0 + tid] = sc;
    }
}

// ---------------------------------------------------------------------------
// softmax over each row of scores [B][S]. grid(B), block(1024): 4 elems/thread.
__global__ __launch_bounds__(1024) void softmax_kernel(const float* __restrict__ scores,
                                                       float* __restrict__ weights) {
    __shared__ float red[16];
    int b = blockIdx.x, tid = threadIdx.x;
    int lane = tid & 63, wid = tid >> 6;
    const float* src = scores + (size_t)b * S;

    float4 v = *(const float4*)(src + tid * 4);
    float m = fmaxf(fmaxf(v.x, v.y), fmaxf(v.z, v.w));
    #pragma unroll
    for (int off = 32; off; off >>= 1) m = fmaxf(m, __shfl_xor(m, off));
    if (lane == 0) red[wid] = m;
    __syncthreads();
    float M = red[0];
    #pragma unroll
    for (int i = 1; i < 16; ++i) M = fmaxf(M, red[i]);
    __syncthreads();

    v.x = __expf(v.x - M);
    v.y = __expf(v.y - M);
    v.z = __expf(v.z - M);
    v.w = __expf(v.w - M);
    float sum = v.x + v.y + v.z + v.w;
    #pragma unroll
    for (int off = 32; off; off >>= 1) sum += __shfl_xor(sum, off);
    if (lane == 0) red[wid] = sum;
    __syncthreads();
    float tot = 0.f;
    #pragma unroll
    for (int i = 0; i < 16; ++i) tot += red[i];
    float inv = 1.f / tot;

    v.x *= inv; v.y *= inv; v.z *= inv; v.w *= inv;
    *(float4*)(weights + (size_t)b * S + tid * 4) = v;
}

// ---------------------------------------------------------------------------
// context[b][h] = sum_s weights[b][s] * keys[b][s][h]
// grid(32 s-chunks, B), block(256); LDS-reduce 4 s-lanes then atomicAdd.
__global__ __launch_bounds__(256) void context_kernel(const float* __restrict__ keys,
                                                      const float* __restrict__ weights,
                                                      float* __restrict__ ctx) {
    int b = blockIdx.y, chunk = blockIdx.x, tid = threadIdx.x;
    __shared__ float w[128];
    if (tid < 128) w[tid] = weights[(size_t)b * S + chunk * 128 + tid];
    __syncthreads();

    int sl = tid >> 6;
    int h4 = (tid & 63) * 4;
    float4 acc = {0.f, 0.f, 0.f, 0.f};
    const float* kb = keys + ((size_t)(b * S + chunk * 128)) * H;
    #pragma unroll 4
    for (int s = sl; s < 128; s += 4) {
        float ws = w[s];
        float4 k4 = *(const float4*)(kb + (size_t)s * H + h4);
        acc.x += ws * k4.x;
        acc.y += ws * k4.y;
        acc.z += ws * k4.z;
        acc.w += ws * k4.w;
    }

    __shared__ float4 partc[4][64];
    partc[sl][tid & 63] = acc;
    __syncthreads();
    if (sl == 0) {
        float4 t = partc[0][tid];
        #pragma unroll
        for (int g = 1; g < 4; ++g) {
            float4 p = partc[g][tid];
            t.x += p.x; t.y += p.y; t.z += p.z; t.w += p.w;
        }
        atomicAdd(&ctx[b * H + h4 + 0], t.x);
        atomicAdd(&ctx[b * H + h4 + 1], t.y);
        atomicAdd(&ctx[b * H + h4 + 2], t.z);
        atomicAdd(&ctx[b * H + h4 + 3], t.w);
    }
}

// ---------------------------------------------------------------------------
extern "C" void kernel_launch(void* const* d_in, const int* in_sizes, int n_in,
                              void* d_out, int out_size, void* d_ws, size_t ws_size,
                              hipStream_t stream) {
    const float* query = (const float*)d_in[0];  // [B,H]
    const float* keys  = (const float*)d_in[1];  // [B,S,H]
    const float* Wq    = (const float*)d_in[2];  // [H,H]
    const float* Wk    = (const float*)d_in[3];  // [H,H]
    const float* V     = (const float*)d_in[4];  // [H]

    float* ctx     = (float*)d_out;            // [B,H]
    float* weights = (float*)d_out + B * H;    // [B,S]

    float* qp            = (float*)d_ws;                       // 16384 f32
    unsigned short* WkHi = (unsigned short*)(qp + B * H);      // 65536 bf16
    unsigned short* WkLo = WkHi + H * H;                       // 65536 bf16
    float* scoresBuf     = (float*)(WkLo + H * H);             // 262144 f32

    hipMemsetAsync(ctx, 0, B * H * sizeof(float), stream);
    wk_split<<<64, 256, 0, stream>>>(Wk, WkHi, WkLo);
    qproj_kernel<<<B, 256, 0, stream>>>(query, Wq, qp);
    scores_kernel<<<dim3(S / BM, B), 512, 0, stream>>>(keys, WkHi, WkLo, qp, V, scoresBuf);
    softmax_kernel<<<B, 1024, 0, stream>>>(scoresBuf, weights);
    context_kernel<<<dim3(32, B), 256, 0, stream>>>(keys, weights, ctx);
}